// Round 1
// baseline (927.268 us; speedup 1.0000x reference)
//
#include <hip/hip_runtime.h>

#define N 8192
#define IN_F 256
#define HEADS 4
#define HF 64
#define OUT_F 256

#define TI 64
#define TJ 64
#define HS 68   // LDS row stride (floats): 68%32=4 -> spreads banks, keeps 16B align

__device__ __forceinline__ float lrelu(float x) {
    // leaky_relu slope 0.2: x>0 -> x ; x<0 -> 0.2x
    return fmaxf(x, 0.0f) * 0.8f + x * 0.2f;
}

// K1: h[head][n][f] = sum_m x[n,m]*w[head,m,f]; wave-reduce coe_i/coe_j
__global__ __launch_bounds__(256) void k_proj(
    const float* __restrict__ x, const float* __restrict__ w,
    const float* __restrict__ wi, const float* __restrict__ wj,
    float* __restrict__ h, float* __restrict__ coe_i, float* __restrict__ coe_j)
{
    int t = threadIdx.x;
    int f = t & 63;
    int n = blockIdx.x * 4 + (t >> 6);
    int head = blockIdx.y;
    const float* xr = x + (size_t)n * IN_F;
    const float* wp = w + (size_t)head * IN_F * HF + f;
    float acc = 0.f;
    #pragma unroll 8
    for (int m = 0; m < IN_F; ++m)
        acc = fmaf(xr[m], wp[(size_t)m * HF], acc);
    h[((size_t)head * N + n) * HF + f] = acc;
    float ci = acc * wi[head * HF + f];
    float cj = acc * wj[head * HF + f];
    #pragma unroll
    for (int o = 32; o > 0; o >>= 1) {
        ci += __shfl_xor(ci, o, 64);
        cj += __shfl_xor(cj, o, 64);
    }
    if (f == 0) {
        coe_i[head * N + n] = ci;
        coe_j[head * N + n] = cj;
    }
}

// K2: maxB[head] = max_j coe_j[head][j]
__global__ __launch_bounds__(256) void k_maxb(
    const float* __restrict__ coe_j, float* __restrict__ maxB)
{
    __shared__ float red[256];
    int head = blockIdx.x;
    int t = threadIdx.x;
    float m = -1e30f;
    for (int n = t; n < N; n += 256)
        m = fmaxf(m, coe_j[head * N + n]);
    red[t] = m;
    __syncthreads();
    for (int s = 128; s > 0; s >>= 1) {
        if (t < s) red[t] = fmaxf(red[t], red[t + s]);
        __syncthreads();
    }
    if (t == 0) maxB[head] = red[0];
}

// K3: out[n][c] = bias[c] + sum_m x[n,m]*wr[m,c]  (residual projection)
__global__ __launch_bounds__(256) void k_res(
    const float* __restrict__ x, const float* __restrict__ wr,
    const float* __restrict__ bias, float* __restrict__ out)
{
    int t = threadIdx.x;
    int n = blockIdx.x;
    const float* xr = x + (size_t)n * IN_F;
    float acc = bias[t];
    #pragma unroll 8
    for (int m = 0; m < IN_F; ++m)
        acc = fmaf(xr[m], wr[(size_t)m * OUT_F + t], acc);
    out[(size_t)n * OUT_F + t] = acc;
}

// K4: flash-style masked softmax-aggregate. Block = (head, 64 rows).
// Thread owns rows (r0, r0+32) x features [f0, f0+8).
__global__ __launch_bounds__(256) void k_att(
    const float* __restrict__ h, const float* __restrict__ coe_i,
    const float* __restrict__ coe_j, const float* __restrict__ maxB,
    const int* __restrict__ graph, float* __restrict__ out)
{
    __shared__ float h_lds[TJ][HS];
    __shared__ float P_lds[TI][HS];
    __shared__ float b_lds[TJ];

    int t = threadIdx.x;
    int head = blockIdx.x;
    int i0 = blockIdx.y * TI;

    int r0 = t >> 3;            // 0..31
    int r1 = r0 + 32;
    int f0 = (t & 7) << 3;      // feature base, also j-base for P compute

    float a0 = coe_i[head * N + i0 + r0];
    float a1 = coe_i[head * N + i0 + r1];
    float mB = maxB[head];
    float M0 = lrelu(a0 + mB);  // valid stabilizer: lrelu monotone
    float M1 = lrelu(a1 + mB);

    float acc0[8] = {0,0,0,0,0,0,0,0};
    float acc1[8] = {0,0,0,0,0,0,0,0};
    float ds0 = 0.f, ds1 = 0.f;

    int js = t >> 2;            // staging row 0..63
    int cb = (t & 3) << 4;      // staging col base 0/16/32/48

    for (int jt = 0; jt < N; jt += TJ) {
        // stage h tile [64 j][64 f]
        {
            const float4* src = (const float4*)(h + ((size_t)head * N + jt + js) * HF + cb);
            float4 v0 = src[0], v1 = src[1], v2 = src[2], v3 = src[3];
            float4* dst = (float4*)&h_lds[js][cb];
            dst[0] = v0; dst[1] = v1; dst[2] = v2; dst[3] = v3;
        }
        // stage mask into P_lds as 0/1: P[i][j] <- graph[j][i] > 0
        {
            const int4* g = (const int4*)(graph + (size_t)(jt + js) * N + i0 + cb);
            int gv[16];
            *(int4*)&gv[0]  = g[0];
            *(int4*)&gv[4]  = g[1];
            *(int4*)&gv[8]  = g[2];
            *(int4*)&gv[12] = g[3];
            #pragma unroll
            for (int k = 0; k < 16; ++k)
                P_lds[cb + k][js] = gv[k] > 0 ? 1.0f : 0.0f;
        }
        if (t < TJ) b_lds[t] = coe_j[head * N + jt + t];
        __syncthreads();

        // P compute: P[i][j] *= exp(lrelu(a_i+b_j) - M_i)   (masked cells stay 0)
        #pragma unroll
        for (int k = 0; k < 8; ++k) {
            float b = b_lds[f0 + k];
            float e0 = __expf(lrelu(a0 + b) - M0);
            float e1 = __expf(lrelu(a1 + b) - M1);
            P_lds[r0][f0 + k] *= e0;
            P_lds[r1][f0 + k] *= e1;
        }
        __syncthreads();

        // accumulate y += P * h, plus denominators
        #pragma unroll 4
        for (int j = 0; j < TJ; ++j) {
            float p0 = P_lds[r0][j];
            float p1 = P_lds[r1][j];
            ds0 += p0;
            ds1 += p1;
            float4 ha = *(const float4*)&h_lds[j][f0];
            float4 hb = *(const float4*)&h_lds[j][f0 + 4];
            acc0[0] = fmaf(p0, ha.x, acc0[0]);
            acc0[1] = fmaf(p0, ha.y, acc0[1]);
            acc0[2] = fmaf(p0, ha.z, acc0[2]);
            acc0[3] = fmaf(p0, ha.w, acc0[3]);
            acc0[4] = fmaf(p0, hb.x, acc0[4]);
            acc0[5] = fmaf(p0, hb.y, acc0[5]);
            acc0[6] = fmaf(p0, hb.z, acc0[6]);
            acc0[7] = fmaf(p0, hb.w, acc0[7]);
            acc1[0] = fmaf(p1, ha.x, acc1[0]);
            acc1[1] = fmaf(p1, ha.y, acc1[1]);
            acc1[2] = fmaf(p1, ha.z, acc1[2]);
            acc1[3] = fmaf(p1, ha.w, acc1[3]);
            acc1[4] = fmaf(p1, hb.x, acc1[4]);
            acc1[5] = fmaf(p1, hb.y, acc1[5]);
            acc1[6] = fmaf(p1, hb.z, acc1[6]);
            acc1[7] = fmaf(p1, hb.w, acc1[7]);
        }
        __syncthreads();
    }

    float inv0 = 1.0f / ds0;
    float inv1 = 1.0f / ds1;
    {
        float4* o = (float4*)(out + (size_t)(i0 + r0) * OUT_F + head * HF + f0);
        float4 v0 = o[0], v1 = o[1];
        v0.x += acc0[0] * inv0; v0.y += acc0[1] * inv0;
        v0.z += acc0[2] * inv0; v0.w += acc0[3] * inv0;
        v1.x += acc0[4] * inv0; v1.y += acc0[5] * inv0;
        v1.z += acc0[6] * inv0; v1.w += acc0[7] * inv0;
        o[0] = v0; o[1] = v1;
    }
    {
        float4* o = (float4*)(out + (size_t)(i0 + r1) * OUT_F + head * HF + f0);
        float4 v0 = o[0], v1 = o[1];
        v0.x += acc1[0] * inv1; v0.y += acc1[1] * inv1;
        v0.z += acc1[2] * inv1; v0.w += acc1[3] * inv1;
        v1.x += acc1[4] * inv1; v1.y += acc1[5] * inv1;
        v1.z += acc1[6] * inv1; v1.w += acc1[7] * inv1;
        o[0] = v0; o[1] = v1;
    }
}

extern "C" void kernel_launch(void* const* d_in, const int* in_sizes, int n_in,
                              void* d_out, int out_size, void* d_ws, size_t ws_size,
                              hipStream_t stream) {
    const float* x     = (const float*)d_in[0];
    const int*   graph = (const int*)d_in[1];
    const float* w     = (const float*)d_in[2];
    const float* wi    = (const float*)d_in[3];
    const float* wj    = (const float*)d_in[4];
    const float* wr    = (const float*)d_in[5];
    const float* bias  = (const float*)d_in[6];
    float* out = (float*)d_out;

    char* ws = (char*)d_ws;
    float* h     = (float*)ws;                                  // 4*8192*64*4 = 8 MB
    float* coe_i = (float*)(ws + (size_t)HEADS * N * HF * 4);   // 128 KB
    float* coe_j = coe_i + (size_t)HEADS * N;                   // 128 KB
    float* maxB  = coe_j + (size_t)HEADS * N;                   // 16 B

    k_proj<<<dim3(N / 4, HEADS), 256, 0, stream>>>(x, w, wi, wj, h, coe_i, coe_j);
    k_maxb<<<dim3(HEADS), 256, 0, stream>>>(coe_j, maxB);
    k_res<<<dim3(N), 256, 0, stream>>>(x, wr, bias, out);
    k_att<<<dim3(HEADS, N / TI), 256, 0, stream>>>(h, coe_i, coe_j, maxB, graph, out);
}

// Round 2
// 389.818 us; speedup vs baseline: 2.3787x; 2.3787x over previous
//
#include <hip/hip_runtime.h>

#define N 8192
#define IN_F 256
#define HEADS 4
#define HF 64
#define OUT_F 256

typedef __attribute__((ext_vector_type(8))) short short8;
typedef __attribute__((ext_vector_type(4))) float f32x4;

__device__ __forceinline__ float lrelu(float x) {
    return fmaxf(x, 0.0f) * 0.8f + x * 0.2f;
}
__device__ __forceinline__ unsigned short f2bf(float f) {
    union { float f; unsigned u; } v; v.f = f;
    unsigned r = v.u + 0x7FFFu + ((v.u >> 16) & 1u);
    return (unsigned short)(r >> 16);
}
__device__ __forceinline__ float bf2f(unsigned short b) {
    union { unsigned u; float f; } v; v.u = ((unsigned)b) << 16;
    return v.f;
}

// K1: h[head][n][f] (bf16) = sum_m x[n,m]*w[head,m,f]; wave-reduce coe_i/coe_j (f32)
__global__ __launch_bounds__(256) void k_proj(
    const float* __restrict__ x, const float* __restrict__ w,
    const float* __restrict__ wi, const float* __restrict__ wj,
    unsigned short* __restrict__ h, float* __restrict__ coe_i, float* __restrict__ coe_j)
{
    int t = threadIdx.x;
    int f = t & 63;
    int n = blockIdx.x * 4 + (t >> 6);
    int head = blockIdx.y;
    const float* xr = x + (size_t)n * IN_F;
    const float* wp = w + (size_t)head * IN_F * HF + f;
    float acc = 0.f;
    #pragma unroll 8
    for (int m = 0; m < IN_F; ++m)
        acc = fmaf(xr[m], wp[(size_t)m * HF], acc);
    h[((size_t)head * N + n) * HF + f] = f2bf(acc);
    float ci = acc * wi[head * HF + f];
    float cj = acc * wj[head * HF + f];
    #pragma unroll
    for (int o = 32; o > 0; o >>= 1) {
        ci += __shfl_xor(ci, o, 64);
        cj += __shfl_xor(cj, o, 64);
    }
    if (f == 0) {
        coe_i[head * N + n] = ci;
        coe_j[head * N + n] = cj;
    }
}

// K2: maxB[head] = max_j coe_j[head][j]
__global__ __launch_bounds__(256) void k_maxb(
    const float* __restrict__ coe_j, float* __restrict__ maxB)
{
    __shared__ float red[256];
    int head = blockIdx.x;
    int t = threadIdx.x;
    float m = -1e30f;
    for (int n = t; n < N; n += 256)
        m = fmaxf(m, coe_j[head * N + n]);
    red[t] = m;
    __syncthreads();
    for (int s = 128; s > 0; s >>= 1) {
        if (t < s) red[t] = fmaxf(red[t], red[t + s]);
        __syncthreads();
    }
    if (t == 0) maxB[head] = red[0];
}

// K3: transpose h[head][n][f] -> hT[head][f][n]  (bf16)
__global__ __launch_bounds__(256) void k_tr(
    const unsigned short* __restrict__ h, unsigned short* __restrict__ hT)
{
    __shared__ unsigned short tl[64 * 66];
    int t = threadIdx.x;
    int head = blockIdx.y;
    int n0 = blockIdx.x * 64;
    int nr = t >> 2;
    int c0 = (t & 3) * 16;
    const unsigned short* src = h + ((size_t)(head * N + n0 + nr) * HF) + c0;
    uint4 v0 = *(const uint4*)src;
    uint4 v1 = *(const uint4*)(src + 8);
    unsigned short e[16];
    *(uint4*)&e[0] = v0;
    *(uint4*)&e[8] = v1;
    #pragma unroll
    for (int k = 0; k < 16; ++k)
        tl[(c0 + k) * 66 + nr] = e[k];
    __syncthreads();
    int f = t >> 2;
    int nc = (t & 3) * 16;
    unsigned int ov[8];
    #pragma unroll
    for (int k = 0; k < 8; ++k)
        ov[k] = *(const unsigned int*)&tl[f * 66 + nc + 2 * k];
    unsigned short* dst = hT + ((size_t)(head * HF + f) * N) + n0 + nc;
    uint4 o0, o1;
    o0.x = ov[0]; o0.y = ov[1]; o0.z = ov[2]; o0.w = ov[3];
    o1.x = ov[4]; o1.y = ov[5]; o1.z = ov[6]; o1.w = ov[7];
    *(uint4*)dst = o0;
    *(uint4*)(dst + 8) = o1;
}

// K4: out[n][c] = bias[c] + sum_m x[n,m]*wr[m,c]  (residual projection, f32)
__global__ __launch_bounds__(256) void k_res(
    const float* __restrict__ x, const float* __restrict__ wr,
    const float* __restrict__ bias, float* __restrict__ out)
{
    int t = threadIdx.x;
    int n = blockIdx.x;
    const float* xr = x + (size_t)n * IN_F;
    float acc = bias[t];
    #pragma unroll 8
    for (int m = 0; m < IN_F; ++m)
        acc = fmaf(xr[m], wr[(size_t)m * OUT_F + t], acc);
    out[(size_t)n * OUT_F + t] = acc;
}

// K5: MFMA flash attention aggregate. Block = (head, 64 rows), 4 waves x 16 rows.
// P computed straight into A-fragments (lane l: row l&15, k = 8*(l>>4)+j).
// B fragments from hT tile in LDS (stride 72 -> 2-way bank alias = free).
__global__ __launch_bounds__(256) void k_att(
    const unsigned short* __restrict__ hT, const float* __restrict__ coe_i,
    const float* __restrict__ coe_j, const float* __restrict__ maxB,
    const int* __restrict__ graph, float* __restrict__ out)
{
    __shared__ unsigned short hT_lds[64 * 72];
    __shared__ float b_lds[64];

    int t = threadIdx.x;
    int head = blockIdx.x;
    int i0 = blockIdx.y * 64;
    int w = t >> 6;
    int l = t & 63;
    int ar = l & 15;           // A-row within 16-row wave tile
    int g  = l >> 4;           // k-group

    int irow = i0 + w * 16 + ar;
    float a = coe_i[head * N + irow];
    float M = lrelu(a + maxB[head]);   // valid stabilizer: lrelu monotone, maxB = max_j b_j

    f32x4 acc[4];
    #pragma unroll
    for (int fb = 0; fb < 4; ++fb) acc[fb] = (f32x4){0.f, 0.f, 0.f, 0.f};
    float dsum = 0.f;

    int sf = t >> 2;
    int sc = t & 3;
    const unsigned short* hrow = hT + ((size_t)(head * HF + sf) * N) + sc * 16;
    unsigned short* ldst = &hT_lds[sf * 72 + sc * 16];

    for (int jt = 0; jt < N; jt += 64) {
        // prefetch stage data into regs before the barrier (overlap with prev MFMA drain)
        uint4 hv0 = *(const uint4*)(hrow + jt);
        uint4 hv1 = *(const uint4*)(hrow + jt + 8);
        float bv = (t < 64) ? coe_j[head * N + jt + t] : 0.f;
        int mk[16];
        #pragma unroll
        for (int s = 0; s < 2; ++s)
            #pragma unroll
            for (int j = 0; j < 8; ++j) {
                int jj = jt + s * 32 + g * 8 + j;
                mk[s * 8 + j] = graph[(size_t)jj * N + irow];
            }
        __syncthreads();   // prev iteration's LDS reads done
        *(uint4*)ldst = hv0;
        *(uint4*)(ldst + 8) = hv1;
        if (t < 64) b_lds[t] = bv;
        __syncthreads();

        // P directly in A-fragment layout; denominator from the SAME rounded values
        short8 afr[2];
        #pragma unroll
        for (int s = 0; s < 2; ++s)
            #pragma unroll
            for (int j = 0; j < 8; ++j) {
                float b = b_lds[s * 32 + g * 8 + j];
                float e = __expf(lrelu(a + b) - M);
                unsigned short eb = (mk[s * 8 + j] > 0) ? f2bf(e) : (unsigned short)0;
                afr[s][j] = (short)eb;
                dsum += bf2f(eb);
            }

        #pragma unroll
        for (int s = 0; s < 2; ++s)
            #pragma unroll
            for (int fb = 0; fb < 4; ++fb) {
                short8 bfr = *(const short8*)&hT_lds[(fb * 16 + ar) * 72 + s * 32 + g * 8];
                acc[fb] = __builtin_amdgcn_mfma_f32_16x16x32_bf16(afr[s], bfr, acc[fb], 0, 0, 0);
            }
    }

    // row sums: combine the 4 k-groups holding the same A-row
    dsum += __shfl_xor(dsum, 16, 64);
    dsum += __shfl_xor(dsum, 32, 64);

    #pragma unroll
    for (int r = 0; r < 4; ++r) {
        int R = g * 4 + r;                         // D-row this lane owns
        float dr = __shfl(dsum, (l & 48) | R, 64); // fetch from lane with ar == R
        float inv = 1.0f / dr;
        int orow = i0 + w * 16 + R;
        float* op = out + (size_t)orow * OUT_F + head * HF + ar;
        #pragma unroll
        for (int fb = 0; fb < 4; ++fb)
            op[fb * 16] += acc[fb][r] * inv;
    }
}

extern "C" void kernel_launch(void* const* d_in, const int* in_sizes, int n_in,
                              void* d_out, int out_size, void* d_ws, size_t ws_size,
                              hipStream_t stream) {
    const float* x     = (const float*)d_in[0];
    const int*   graph = (const int*)d_in[1];
    const float* w     = (const float*)d_in[2];
    const float* wi    = (const float*)d_in[3];
    const float* wj    = (const float*)d_in[4];
    const float* wr    = (const float*)d_in[5];
    const float* bias  = (const float*)d_in[6];
    float* out = (float*)d_out;

    char* ws = (char*)d_ws;
    unsigned short* hb = (unsigned short*)ws;                        // 4 MB
    unsigned short* hT = (unsigned short*)(ws + (size_t)4194304);    // 4 MB
    float* coe_i = (float*)(ws + (size_t)8388608);                   // 128 KB
    float* coe_j = coe_i + (size_t)HEADS * N;                        // 128 KB
    float* maxB  = coe_j + (size_t)HEADS * N;                        // 16 B

    k_proj<<<dim3(N / 4, HEADS), 256, 0, stream>>>(x, w, wi, wj, hb, coe_i, coe_j);
    k_maxb<<<dim3(HEADS), 256, 0, stream>>>(coe_j, maxB);
    k_tr<<<dim3(N / 64, HEADS), 256, 0, stream>>>(hb, hT);
    k_res<<<dim3(N), 256, 0, stream>>>(x, wr, bias, out);
    k_att<<<dim3(HEADS, N / 64), 256, 0, stream>>>(hT, coe_i, coe_j, maxB, graph, out);
}

// Round 3
// 214.421 us; speedup vs baseline: 4.3245x; 1.8180x over previous
//
#include <hip/hip_runtime.h>
#include <hip/hip_bf16.h>

#define N 8192
#define IN_F 256
#define HEADS 4
#define HF 64
#define OUT_F 256

typedef __attribute__((ext_vector_type(8))) short short8;
typedef __attribute__((ext_vector_type(4))) float f32x4;

__device__ __forceinline__ float lrelu(float x) {
    return fmaxf(x, 0.0f) * 0.8f + x * 0.2f;
}
__device__ __forceinline__ short f2bf(float f) {
    union { __hip_bfloat16 h; short s; } u;
    u.h = __float2bfloat16(f);
    return u.s;
}
__device__ __forceinline__ float bf2f(unsigned short b) {
    union { unsigned u; float f; } v; v.u = ((unsigned)b) << 16;
    return v.f;
}

// K0: build BbT[c][k] bf16, c<256 -> W heads, c>=256 -> Wr
__global__ __launch_bounds__(256) void k_wcvt(
    const float* __restrict__ w, const float* __restrict__ wr,
    unsigned short* __restrict__ BbT)
{
    int c = blockIdx.x;
    int k = threadIdx.x;
    float v;
    if (c < 256) {
        int head = c >> 6, f = c & 63;
        v = w[((size_t)head * IN_F + k) * HF + f];
    } else {
        v = wr[(size_t)k * OUT_F + (c - 256)];
    }
    BbT[(size_t)c * IN_F + k] = (unsigned short)f2bf(v);
}

// K1: fused GEMM  [8192x256] @ [256x512] -> h (cols 0..255, bf16) | out residual (cols 256..511, f32)
__global__ __launch_bounds__(256) void k_gemm(
    const float* __restrict__ x, const unsigned short* __restrict__ BbT,
    const float* __restrict__ bias,
    unsigned short* __restrict__ h, float* __restrict__ out)
{
    __shared__ unsigned short Asw[64 * 64];
    __shared__ unsigned short Bsw[128 * 64];
    int t = threadIdx.x;
    int m0 = blockIdx.x * 64;
    int bn = blockIdx.y;
    int w_ = t >> 6, l = t & 63;
    int wr_ = w_ >> 1, wc_ = w_ & 1;
    int ar = l & 15, g = l >> 4;

    f32x4 acc[2][4];
    #pragma unroll
    for (int m = 0; m < 2; ++m)
        #pragma unroll
        for (int n = 0; n < 4; ++n) acc[m][n] = (f32x4){0.f, 0.f, 0.f, 0.f};

    int srow = t >> 2, skq = (t & 3) * 16;
    int sc = t >> 1, sh = (t & 1) * 32;

    for (int kt = 0; kt < 4; ++kt) {
        // stage A (f32 -> bf16, swizzled)
        const float* xs = x + (size_t)(m0 + srow) * IN_F + kt * 64 + skq;
        float4 xa = ((const float4*)xs)[0];
        float4 xb = ((const float4*)xs)[1];
        float4 xc = ((const float4*)xs)[2];
        float4 xd = ((const float4*)xs)[3];
        unsigned short ae[16];
        ae[0] = f2bf(xa.x); ae[1] = f2bf(xa.y); ae[2] = f2bf(xa.z); ae[3] = f2bf(xa.w);
        ae[4] = f2bf(xb.x); ae[5] = f2bf(xb.y); ae[6] = f2bf(xb.z); ae[7] = f2bf(xb.w);
        ae[8] = f2bf(xc.x); ae[9] = f2bf(xc.y); ae[10] = f2bf(xc.z); ae[11] = f2bf(xc.w);
        ae[12] = f2bf(xd.x); ae[13] = f2bf(xd.y); ae[14] = f2bf(xd.z); ae[15] = f2bf(xd.w);
        int kb0 = (skq >> 3) ^ (srow & 7);
        int kb1 = ((skq >> 3) + 1) ^ (srow & 7);
        *(uint4*)&Asw[srow * 64 + kb0 * 8] = *(uint4*)&ae[0];
        *(uint4*)&Asw[srow * 64 + kb1 * 8] = *(uint4*)&ae[8];
        // stage B (bf16, swizzled)
        const unsigned short* bs = BbT + (size_t)(bn * 128 + sc) * IN_F + kt * 64 + sh;
        uint4 b0 = ((const uint4*)bs)[0];
        uint4 b1 = ((const uint4*)bs)[1];
        uint4 b2 = ((const uint4*)bs)[2];
        uint4 b3 = ((const uint4*)bs)[3];
        int hb = sh >> 3;
        *(uint4*)&Bsw[sc * 64 + ((hb + 0) ^ (sc & 7)) * 8] = b0;
        *(uint4*)&Bsw[sc * 64 + ((hb + 1) ^ (sc & 7)) * 8] = b1;
        *(uint4*)&Bsw[sc * 64 + ((hb + 2) ^ (sc & 7)) * 8] = b2;
        *(uint4*)&Bsw[sc * 64 + ((hb + 3) ^ (sc & 7)) * 8] = b3;
        __syncthreads();
        #pragma unroll
        for (int ks = 0; ks < 2; ++ks) {
            short8 af[2], bf[4];
            #pragma unroll
            for (int m = 0; m < 2; ++m) {
                int row = wr_ * 32 + m * 16 + ar;
                int kb = (ks * 4 + g) ^ (row & 7);
                af[m] = *(const short8*)&Asw[row * 64 + kb * 8];
            }
            #pragma unroll
            for (int n = 0; n < 4; ++n) {
                int c = wc_ * 64 + n * 16 + ar;
                int kb = (ks * 4 + g) ^ (c & 7);
                bf[n] = *(const short8*)&Bsw[c * 64 + kb * 8];
            }
            #pragma unroll
            for (int m = 0; m < 2; ++m)
                #pragma unroll
                for (int n = 0; n < 4; ++n)
                    acc[m][n] = __builtin_amdgcn_mfma_f32_16x16x32_bf16(af[m], bf[n], acc[m][n], 0, 0, 0);
        }
        __syncthreads();
    }
    #pragma unroll
    for (int m = 0; m < 2; ++m) {
        #pragma unroll
        for (int n = 0; n < 4; ++n) {
            int cg = bn * 128 + wc_ * 64 + n * 16 + ar;
            #pragma unroll
            for (int r = 0; r < 4; ++r) {
                int mg = m0 + wr_ * 32 + m * 16 + g * 4 + r;
                float v = acc[m][n][r];
                if (cg < 256) {
                    int head = cg >> 6, f = cg & 63;
                    h[((size_t)head * N + mg) * HF + f] = (unsigned short)f2bf(v);
                } else {
                    out[(size_t)mg * OUT_F + (cg - 256)] = v + bias[cg - 256];
                }
            }
        }
    }
}

// K2: transpose h -> hT, and reduce coe_i/coe_j
__global__ __launch_bounds__(256) void k_tr(
    const unsigned short* __restrict__ h, const float* __restrict__ wi,
    const float* __restrict__ wj,
    unsigned short* __restrict__ hT, float* __restrict__ coe_i, float* __restrict__ coe_j)
{
    __shared__ unsigned short tl[64 * 66];
    __shared__ float red_i[4][64];
    __shared__ float red_j[4][64];
    int t = threadIdx.x;
    int head = blockIdx.y;
    int n0 = blockIdx.x * 64;
    int nr = t >> 2, c0 = (t & 3) * 16;
    const unsigned short* src = h + ((size_t)(head * N + n0 + nr) * HF) + c0;
    uint4 v0 = *(const uint4*)src;
    uint4 v1 = *(const uint4*)(src + 8);
    unsigned short e[16];
    *(uint4*)&e[0] = v0;
    *(uint4*)&e[8] = v1;
    #pragma unroll
    for (int k = 0; k < 16; ++k)
        tl[(c0 + k) * 66 + nr] = e[k];
    __syncthreads();
    int f = t >> 2, nc = (t & 3) * 16;
    unsigned int ov[8];
    #pragma unroll
    for (int k = 0; k < 8; ++k)
        ov[k] = *(const unsigned int*)&tl[f * 66 + nc + 2 * k];
    unsigned short* dst = hT + ((size_t)(head * HF + f) * N) + n0 + nc;
    uint4 o0, o1;
    o0.x = ov[0]; o0.y = ov[1]; o0.z = ov[2]; o0.w = ov[3];
    o1.x = ov[4]; o1.y = ov[5]; o1.z = ov[6]; o1.w = ov[7];
    *(uint4*)dst = o0;
    *(uint4*)(dst + 8) = o1;
    // coe reductions
    int q = t >> 6, nn = t & 63;
    float pi = 0.f, pj = 0.f;
    #pragma unroll
    for (int k = 0; k < 16; ++k) {
        int ff = q * 16 + k;
        float hv = bf2f(tl[ff * 66 + nn]);
        pi = fmaf(hv, wi[head * HF + ff], pi);
        pj = fmaf(hv, wj[head * HF + ff], pj);
    }
    red_i[q][nn] = pi;
    red_j[q][nn] = pj;
    __syncthreads();
    if (t < 64) {
        float si = red_i[0][t] + red_i[1][t] + red_i[2][t] + red_i[3][t];
        float sj = red_j[0][t] + red_j[1][t] + red_j[2][t] + red_j[3][t];
        coe_i[head * N + n0 + t] = si;
        coe_j[head * N + n0 + t] = sj;
    }
}

// K3: per head: maxB + column factor arrays F=exp(b), H=exp(0.2b)
__global__ __launch_bounds__(256) void k_cols(
    const float* __restrict__ coe_j, float* __restrict__ maxB,
    float* __restrict__ F, float* __restrict__ H)
{
    __shared__ float red[256];
    int head = blockIdx.x;
    int t = threadIdx.x;
    float m = -1e30f;
    for (int n = t; n < N; n += 256) {
        float b = coe_j[head * N + n];
        F[head * N + n] = __expf(b);
        H[head * N + n] = __expf(0.2f * b);
        m = fmaxf(m, b);
    }
    red[t] = m;
    __syncthreads();
    for (int s = 128; s > 0; s >>= 1) {
        if (t < s) red[t] = fmaxf(red[t], red[t + s]);
        __syncthreads();
    }
    if (t == 0) maxB[head] = red[0];
}

// K4: pack graph -> bits[jw][i]: bit k of word = graph[jw*32+k][i] > 0
__global__ __launch_bounds__(256) void k_pack(
    const int* __restrict__ graph, unsigned int* __restrict__ bits)
{
    int i = blockIdx.y * 256 + threadIdx.x;
    int jw = blockIdx.x;
    const int* gp = graph + (size_t)(jw * 32) * N + i;
    unsigned int word = 0;
    #pragma unroll
    for (int k = 0; k < 32; ++k)
        word |= (gp[(size_t)k * N] > 0 ? 1u : 0u) << k;
    bits[(size_t)jw * N + i] = word;
}

__device__ __forceinline__ void compute8(short8& af, int base,
    const float4& fa, const float4& fb, const float4& ha, const float4& hb,
    unsigned int mk, float Ei, float Gi, float nEa)
{
    float fv[8] = {fa.x, fa.y, fa.z, fa.w, fb.x, fb.y, fb.z, fb.w};
    float hv[8] = {ha.x, ha.y, ha.z, ha.w, hb.x, hb.y, hb.z, hb.w};
    #pragma unroll
    for (int j = 0; j < 8; ++j) {
        bool c = fv[j] > nEa;
        float p = (c ? Ei : Gi) * (c ? fv[j] : hv[j]);
        p = (mk & (1u << j)) ? p : 0.0f;
        af[j] = f2bf(p);
    }
    (void)base;
}

// K5: flash aggregate, factored P, bitmask, ones-MFMA denominator, double-buffered LDS
__global__ __launch_bounds__(256) void k_att(
    const unsigned short* __restrict__ hT, const float* __restrict__ coe_i,
    const float* __restrict__ maxB, const float* __restrict__ F,
    const float* __restrict__ H, const unsigned int* __restrict__ bits,
    float* __restrict__ out)
{
    __shared__ unsigned short hT_lds[2][64 * 72];

    int t = threadIdx.x;
    int head = blockIdx.x;
    int i0 = blockIdx.y * 64;
    int w = t >> 6, l = t & 63;
    int ar = l & 15, g = l >> 4;
    int g8 = g * 8;

    int irow = i0 + w * 16 + ar;
    float a = coe_i[head * N + irow];
    float M = lrelu(a + maxB[head]);
    float Ei = __expf(a - M);
    float Gi = __expf(0.2f * a - M);
    float nEa = __expf(-a);

    f32x4 acc[4];
    #pragma unroll
    for (int fb = 0; fb < 4; ++fb) acc[fb] = (f32x4){0.f, 0.f, 0.f, 0.f};
    f32x4 accd = (f32x4){0.f, 0.f, 0.f, 0.f};

    short8 ones;
    #pragma unroll
    for (int k = 0; k < 8; ++k) ones[k] = (short)0x3F80;

    int sf = t >> 2, scb = (t & 3) * 16;
    const unsigned short* hrow = hT + ((size_t)(head * HF + sf) * N) + scb;
    unsigned short* ldstA = &hT_lds[0][sf * 72 + scb];
    unsigned short* ldstB = &hT_lds[1][sf * 72 + scb];

    const float* Fp = F + head * N + g8;
    const float* Hp = H + head * N + g8;
    const unsigned int* bp = bits + irow;

    uint4 hv0 = *(const uint4*)(hrow);
    uint4 hv1 = *(const uint4*)(hrow + 8);
    *(uint4*)ldstA = hv0;
    *(uint4*)(ldstA + 8) = hv1;
    __syncthreads();

    for (int jt = 0; jt < N; jt += 64) {
        int rd = (jt >> 6) & 1;
        unsigned short* ldst = rd ? ldstA : ldstB;   // write buffer = rd^1
        bool more = (jt + 64) < N;
        if (more) {
            hv0 = *(const uint4*)(hrow + jt + 64);
            hv1 = *(const uint4*)(hrow + jt + 72);
        }
        unsigned int mk0 = bp[(size_t)(jt >> 5) * N] >> g8;
        unsigned int mk1 = bp[(size_t)((jt >> 5) + 1) * N] >> g8;
        float4 f0 = *(const float4*)(Fp + jt);
        float4 f1 = *(const float4*)(Fp + jt + 4);
        float4 f2 = *(const float4*)(Fp + jt + 32);
        float4 f3 = *(const float4*)(Fp + jt + 36);
        float4 h0 = *(const float4*)(Hp + jt);
        float4 h1 = *(const float4*)(Hp + jt + 4);
        float4 h2 = *(const float4*)(Hp + jt + 32);
        float4 h3 = *(const float4*)(Hp + jt + 36);

        short8 af0, af1;
        compute8(af0, 0, f0, f1, h0, h1, mk0, Ei, Gi, nEa);
        compute8(af1, 0, f2, f3, h2, h3, mk1, Ei, Gi, nEa);

        #pragma unroll
        for (int ss = 0; ss < 2; ++ss) {
            short8 af = ss ? af1 : af0;
            #pragma unroll
            for (int fb = 0; fb < 4; ++fb) {
                short8 bfr = *(const short8*)&hT_lds[rd][(fb * 16 + ar) * 72 + ss * 32 + g8];
                acc[fb] = __builtin_amdgcn_mfma_f32_16x16x32_bf16(af, bfr, acc[fb], 0, 0, 0);
            }
            accd = __builtin_amdgcn_mfma_f32_16x16x32_bf16(af, ones, accd, 0, 0, 0);
        }
        if (more) {
            *(uint4*)ldst = hv0;
            *(uint4*)(ldst + 8) = hv1;
        }
        __syncthreads();
    }

    #pragma unroll
    for (int r = 0; r < 4; ++r) {
        float inv = 1.0f / accd[r];
        int orow = i0 + w * 16 + g * 4 + r;
        float* op = out + (size_t)orow * OUT_F + head * HF + ar;
        #pragma unroll
        for (int fb = 0; fb < 4; ++fb)
            op[fb * 16] += acc[fb][r] * inv;
    }
}

extern "C" void kernel_launch(void* const* d_in, const int* in_sizes, int n_in,
                              void* d_out, int out_size, void* d_ws, size_t ws_size,
                              hipStream_t stream) {
    const float* x     = (const float*)d_in[0];
    const int*   graph = (const int*)d_in[1];
    const float* w     = (const float*)d_in[2];
    const float* wi    = (const float*)d_in[3];
    const float* wj    = (const float*)d_in[4];
    const float* wr    = (const float*)d_in[5];
    const float* bias  = (const float*)d_in[6];
    float* out = (float*)d_out;

    char* ws = (char*)d_ws;
    unsigned short* h   = (unsigned short*)(ws);
    unsigned short* hT  = (unsigned short*)(ws + (4u << 20));
    float* coe_i = (float*)(ws + (8u << 20));
    float* coe_j = (float*)(ws + (8u << 20) + 131072);
    float* maxB  = (float*)(ws + (8u << 20) + 2 * 131072);
    float* F     = (float*)(ws + (8u << 20) + 2 * 131072 + 1024);
    float* H     = (float*)(ws + (8u << 20) + 3 * 131072 + 1024);
    unsigned short* BbT = (unsigned short*)(ws + (8u << 20) + 4 * 131072 + 1024);
    unsigned int* bits  = (unsigned int*)(ws + (8u << 20) + 4 * 131072 + 1024 + 262144);

    k_wcvt<<<dim3(512), 256, 0, stream>>>(w, wr, BbT);
    k_gemm<<<dim3(128, 4), 256, 0, stream>>>(x, BbT, bias, h, out);
    k_tr<<<dim3(128, 4), 256, 0, stream>>>(h, wi, wj, hT, coe_i, coe_j);
    k_cols<<<dim3(4), 256, 0, stream>>>(coe_j, maxB, F, H);
    k_pack<<<dim3(256, 32), 256, 0, stream>>>(graph, bits);
    k_att<<<dim3(HEADS, N / 64), 256, 0, stream>>>(hT, coe_i, maxB, F, H, bits, out);
}

// Round 4
// 180.865 us; speedup vs baseline: 5.1269x; 1.1855x over previous
//
#include <hip/hip_runtime.h>
#include <hip/hip_bf16.h>

#define N 8192
#define IN_F 256
#define HEADS 4
#define HF 64
#define OUT_F 256

typedef __attribute__((ext_vector_type(8))) short short8;
typedef __attribute__((ext_vector_type(4))) float f32x4;

__device__ __forceinline__ float lrelu(float x) {
    return fmaxf(x, 0.0f) * 0.8f + x * 0.2f;
}
__device__ __forceinline__ short f2bf(float f) {
    union { __hip_bfloat16 h; short s; } u;
    u.h = __float2bfloat16(f);
    return u.s;
}
__device__ __forceinline__ float bf2f(unsigned short b) {
    union { unsigned u; float f; } v; v.u = ((unsigned)b) << 16;
    return v.f;
}

// K0: build BbT[c][k] bf16, c<256 -> W heads, c>=256 -> Wr
__global__ __launch_bounds__(256) void k_wcvt(
    const float* __restrict__ w, const float* __restrict__ wr,
    unsigned short* __restrict__ BbT)
{
    int c = blockIdx.x;
    int k = threadIdx.x;
    float v;
    if (c < 256) {
        int head = c >> 6, f = c & 63;
        v = w[((size_t)head * IN_F + k) * HF + f];
    } else {
        v = wr[(size_t)k * OUT_F + (c - 256)];
    }
    BbT[(size_t)c * IN_F + k] = (unsigned short)f2bf(v);
}

// K1: fused GEMM  [8192x256] @ [256x512] -> h (cols 0..255, bf16) | out residual (cols 256..511, f32)
__global__ __launch_bounds__(256) void k_gemm(
    const float* __restrict__ x, const unsigned short* __restrict__ BbT,
    const float* __restrict__ bias,
    unsigned short* __restrict__ h, float* __restrict__ out)
{
    __shared__ unsigned short Asw[64 * 64];
    __shared__ unsigned short Bsw[128 * 64];
    int t = threadIdx.x;
    int m0 = blockIdx.x * 64;
    int bn = blockIdx.y;
    int w_ = t >> 6, l = t & 63;
    int wr_ = w_ >> 1, wc_ = w_ & 1;
    int ar = l & 15, g = l >> 4;

    f32x4 acc[2][4];
    #pragma unroll
    for (int m = 0; m < 2; ++m)
        #pragma unroll
        for (int n = 0; n < 4; ++n) acc[m][n] = (f32x4){0.f, 0.f, 0.f, 0.f};

    int srow = t >> 2, skq = (t & 3) * 16;
    int sc = t >> 1, sh = (t & 1) * 32;

    for (int kt = 0; kt < 4; ++kt) {
        const float* xs = x + (size_t)(m0 + srow) * IN_F + kt * 64 + skq;
        float4 xa = ((const float4*)xs)[0];
        float4 xb = ((const float4*)xs)[1];
        float4 xc = ((const float4*)xs)[2];
        float4 xd = ((const float4*)xs)[3];
        unsigned short ae[16];
        ae[0] = f2bf(xa.x); ae[1] = f2bf(xa.y); ae[2] = f2bf(xa.z); ae[3] = f2bf(xa.w);
        ae[4] = f2bf(xb.x); ae[5] = f2bf(xb.y); ae[6] = f2bf(xb.z); ae[7] = f2bf(xb.w);
        ae[8] = f2bf(xc.x); ae[9] = f2bf(xc.y); ae[10] = f2bf(xc.z); ae[11] = f2bf(xc.w);
        ae[12] = f2bf(xd.x); ae[13] = f2bf(xd.y); ae[14] = f2bf(xd.z); ae[15] = f2bf(xd.w);
        int kb0 = (skq >> 3) ^ (srow & 7);
        int kb1 = ((skq >> 3) + 1) ^ (srow & 7);
        *(uint4*)&Asw[srow * 64 + kb0 * 8] = *(uint4*)&ae[0];
        *(uint4*)&Asw[srow * 64 + kb1 * 8] = *(uint4*)&ae[8];
        const unsigned short* bs = BbT + (size_t)(bn * 128 + sc) * IN_F + kt * 64 + sh;
        uint4 b0 = ((const uint4*)bs)[0];
        uint4 b1 = ((const uint4*)bs)[1];
        uint4 b2 = ((const uint4*)bs)[2];
        uint4 b3 = ((const uint4*)bs)[3];
        int hb = sh >> 3;
        *(uint4*)&Bsw[sc * 64 + ((hb + 0) ^ (sc & 7)) * 8] = b0;
        *(uint4*)&Bsw[sc * 64 + ((hb + 1) ^ (sc & 7)) * 8] = b1;
        *(uint4*)&Bsw[sc * 64 + ((hb + 2) ^ (sc & 7)) * 8] = b2;
        *(uint4*)&Bsw[sc * 64 + ((hb + 3) ^ (sc & 7)) * 8] = b3;
        __syncthreads();
        #pragma unroll
        for (int ks = 0; ks < 2; ++ks) {
            short8 af[2], bf[4];
            #pragma unroll
            for (int m = 0; m < 2; ++m) {
                int row = wr_ * 32 + m * 16 + ar;
                int kb = (ks * 4 + g) ^ (row & 7);
                af[m] = *(const short8*)&Asw[row * 64 + kb * 8];
            }
            #pragma unroll
            for (int n = 0; n < 4; ++n) {
                int c = wc_ * 64 + n * 16 + ar;
                int kb = (ks * 4 + g) ^ (c & 7);
                bf[n] = *(const short8*)&Bsw[c * 64 + kb * 8];
            }
            #pragma unroll
            for (int m = 0; m < 2; ++m)
                #pragma unroll
                for (int n = 0; n < 4; ++n)
                    acc[m][n] = __builtin_amdgcn_mfma_f32_16x16x32_bf16(af[m], bf[n], acc[m][n], 0, 0, 0);
        }
        __syncthreads();
    }
    #pragma unroll
    for (int m = 0; m < 2; ++m) {
        #pragma unroll
        for (int n = 0; n < 4; ++n) {
            int cg = bn * 128 + wc_ * 64 + n * 16 + ar;
            #pragma unroll
            for (int r = 0; r < 4; ++r) {
                int mg = m0 + wr_ * 32 + m * 16 + g * 4 + r;
                float v = acc[m][n][r];
                if (cg < 256) {
                    int head = cg >> 6, f = cg & 63;
                    h[((size_t)head * N + mg) * HF + f] = (unsigned short)f2bf(v);
                } else {
                    out[(size_t)mg * OUT_F + (cg - 256)] = v + bias[cg - 256];
                }
            }
        }
    }
}

// K2: transpose h -> hT, and reduce coe_i/coe_j
__global__ __launch_bounds__(256) void k_tr(
    const unsigned short* __restrict__ h, const float* __restrict__ wi,
    const float* __restrict__ wj,
    unsigned short* __restrict__ hT, float* __restrict__ coe_i, float* __restrict__ coe_j)
{
    __shared__ unsigned short tl[64 * 66];
    __shared__ float red_i[4][64];
    __shared__ float red_j[4][64];
    int t = threadIdx.x;
    int head = blockIdx.y;
    int n0 = blockIdx.x * 64;
    int nr = t >> 2, c0 = (t & 3) * 16;
    const unsigned short* src = h + ((size_t)(head * N + n0 + nr) * HF) + c0;
    uint4 v0 = *(const uint4*)src;
    uint4 v1 = *(const uint4*)(src + 8);
    unsigned short e[16];
    *(uint4*)&e[0] = v0;
    *(uint4*)&e[8] = v1;
    #pragma unroll
    for (int k = 0; k < 16; ++k)
        tl[(c0 + k) * 66 + nr] = e[k];
    __syncthreads();
    int f = t >> 2, nc = (t & 3) * 16;
    unsigned int ov[8];
    #pragma unroll
    for (int k = 0; k < 8; ++k)
        ov[k] = *(const unsigned int*)&tl[f * 66 + nc + 2 * k];
    unsigned short* dst = hT + ((size_t)(head * HF + f) * N) + n0 + nc;
    uint4 o0, o1;
    o0.x = ov[0]; o0.y = ov[1]; o0.z = ov[2]; o0.w = ov[3];
    o1.x = ov[4]; o1.y = ov[5]; o1.z = ov[6]; o1.w = ov[7];
    *(uint4*)dst = o0;
    *(uint4*)(dst + 8) = o1;
    int q = t >> 6, nn = t & 63;
    float pi = 0.f, pj = 0.f;
    #pragma unroll
    for (int k = 0; k < 16; ++k) {
        int ff = q * 16 + k;
        float hv = bf2f(tl[ff * 66 + nn]);
        pi = fmaf(hv, wi[head * HF + ff], pi);
        pj = fmaf(hv, wj[head * HF + ff], pj);
    }
    red_i[q][nn] = pi;
    red_j[q][nn] = pj;
    __syncthreads();
    if (t < 64) {
        float si = red_i[0][t] + red_i[1][t] + red_i[2][t] + red_i[3][t];
        float sj = red_j[0][t] + red_j[1][t] + red_j[2][t] + red_j[3][t];
        coe_i[head * N + n0 + t] = si;
        coe_j[head * N + n0 + t] = sj;
    }
}

// K3: per head: maxB + column factor arrays F=exp(b), H=exp(0.2b)
__global__ __launch_bounds__(256) void k_cols(
    const float* __restrict__ coe_j, float* __restrict__ maxB,
    float* __restrict__ F, float* __restrict__ H)
{
    __shared__ float red[256];
    int head = blockIdx.x;
    int t = threadIdx.x;
    float m = -1e30f;
    for (int n = t; n < N; n += 256) {
        float b = coe_j[head * N + n];
        F[head * N + n] = __expf(b);
        H[head * N + n] = __expf(0.2f * b);
        m = fmaxf(m, b);
    }
    red[t] = m;
    __syncthreads();
    for (int s = 128; s > 0; s >>= 1) {
        if (t < s) red[t] = fmaxf(red[t], red[t + s]);
        __syncthreads();
    }
    if (t == 0) maxB[head] = red[0];
}

// K4: pack graph -> bits[jw][i]: bit k of word = graph[jw*32+k][i] > 0
__global__ __launch_bounds__(256) void k_pack(
    const int* __restrict__ graph, unsigned int* __restrict__ bits)
{
    int i = blockIdx.y * 256 + threadIdx.x;
    int jw = blockIdx.x;
    const int* gp = graph + (size_t)(jw * 32) * N + i;
    unsigned int word = 0;
    #pragma unroll
    for (int k = 0; k < 32; ++k)
        word |= (gp[(size_t)k * N] > 0 ? 1u : 0u) << k;
    bits[(size_t)jw * N + i] = word;
}

// P for 8 columns: p = max(Ei*F, Gi*H)   [= exp(lrelu(a+b)-M), exp monotone]
__device__ __forceinline__ void computeP(short8& af,
    const float4& fa, const float4& fb, const float4& ha, const float4& hb,
    unsigned int mk, float Ei, float Gi)
{
    float fv[8] = {fa.x, fa.y, fa.z, fa.w, fb.x, fb.y, fb.z, fb.w};
    float hv[8] = {ha.x, ha.y, ha.z, ha.w, hb.x, hb.y, hb.z, hb.w};
    #pragma unroll
    for (int j = 0; j < 8; ++j) {
        float p = fmaxf(Ei * fv[j], Gi * hv[j]);
        p = (mk & (1u << j)) ? p : 0.0f;
        af[j] = f2bf(p);
    }
}

// K5: flash aggregate. 512 threads = 8 waves. Wave pair (w, w+4) owns rows
// [.. (w&3)*16 ..); group A (w<4) does even j-tiles, group B odd. Both tiles
// staged cooperatively per 128-j super-iteration into XOR-swizzled LDS.
__global__ __launch_bounds__(512) void k_att(
    const unsigned short* __restrict__ hT, const float* __restrict__ coe_i,
    const float* __restrict__ maxB, const float* __restrict__ F,
    const float* __restrict__ H, const unsigned int* __restrict__ bits,
    float* __restrict__ out)
{
    __shared__ unsigned short hbuf[2][64 * 64];   // [f row][swizzled 16B granules]
    __shared__ float mbuf[4 * 64 * 21];           // merge buffer (pad 21: bank-friendly)

    int t = threadIdx.x;
    int head = blockIdx.x;
    int i0 = blockIdx.y * 64;
    int w = t >> 6;           // 0..7
    int l = t & 63;
    int wrow = w & 3;         // row-group 0..3
    int grp = w >> 2;         // 0 = even tiles, 1 = odd tiles
    int ar = l & 15, g = l >> 4, g8 = g * 8;

    int irow = i0 + wrow * 16 + ar;
    float a = coe_i[head * N + irow];
    float M = lrelu(a + maxB[head]);
    float Ei = __expf(a - M);
    float Gi = __expf(0.2f * a - M);

    f32x4 acc[4];
    #pragma unroll
    for (int fb = 0; fb < 4; ++fb) acc[fb] = (f32x4){0.f, 0.f, 0.f, 0.f};
    f32x4 accd = (f32x4){0.f, 0.f, 0.f, 0.f};

    short8 ones;
    #pragma unroll
    for (int k = 0; k < 8; ++k) ones[k] = (short)0x3F80;

    // staging role: thread t stages 16 consecutive j of feature-row sf into buffer sbuf
    int sbuf = t >> 8;             // 0 or 1
    int u = t & 255;
    int sf = u >> 2;               // 0..63
    int sj = (u & 3) * 16;         // 0/16/32/48
    const unsigned short* hrow = hT + ((size_t)(head * HF + sf) * N) + sj;
    int pg0 = ((sj >> 3) + 0) ^ (sf & 7);
    int pg1 = ((sj >> 3) + 1) ^ (sf & 7);
    unsigned short* wp0 = &hbuf[sbuf][sf * 64 + pg0 * 8];
    unsigned short* wp1 = &hbuf[sbuf][sf * 64 + pg1 * 8];

    const float* Fp = F + head * N + g8;
    const float* Hp = H + head * N + g8;
    const unsigned int* bp = bits + irow;

    for (int jt0 = 0; jt0 < N; jt0 += 128) {
        int jt = jt0 + grp * 64;   // this wave's compute tile
        // prefetch staging data (issued before barrier; overlaps other waves' compute)
        uint4 hv0 = *(const uint4*)(hrow + jt0 + sbuf * 64);
        uint4 hv1 = *(const uint4*)(hrow + jt0 + sbuf * 64 + 8);
        unsigned int mk0 = bp[(size_t)((jt >> 5) + 0) * N] >> g8;
        unsigned int mk1 = bp[(size_t)((jt >> 5) + 1) * N] >> g8;
        float4 f0 = *(const float4*)(Fp + jt);
        float4 f1 = *(const float4*)(Fp + jt + 4);
        float4 f2 = *(const float4*)(Fp + jt + 32);
        float4 f3 = *(const float4*)(Fp + jt + 36);
        float4 h0 = *(const float4*)(Hp + jt);
        float4 h1 = *(const float4*)(Hp + jt + 4);
        float4 h2 = *(const float4*)(Hp + jt + 32);
        float4 h3 = *(const float4*)(Hp + jt + 36);

        __syncthreads();           // previous compute's LDS reads complete
        *(uint4*)wp0 = hv0;
        *(uint4*)wp1 = hv1;
        __syncthreads();           // both buffers ready

        short8 af0, af1;
        computeP(af0, f0, f1, h0, h1, mk0, Ei, Gi);
        computeP(af1, f2, f3, h2, h3, mk1, Ei, Gi);

        #pragma unroll
        for (int ss = 0; ss < 2; ++ss) {
            short8 af = ss ? af1 : af0;
            #pragma unroll
            for (int fb = 0; fb < 4; ++fb) {
                int row = fb * 16 + ar;
                int pg = (ss * 4 + g) ^ (ar & 7);   // (row&7)==(ar&7)
                short8 bfr = *(const short8*)&hbuf[grp][row * 64 + pg * 8];
                acc[fb] = __builtin_amdgcn_mfma_f32_16x16x32_bf16(af, bfr, acc[fb], 0, 0, 0);
            }
            accd = __builtin_amdgcn_mfma_f32_16x16x32_bf16(af, ones, accd, 0, 0, 0);
        }
    }

    __syncthreads();               // all compute done before reusing LDS
    int mb = (wrow * 64 + l) * 21;
    if (grp == 1) {
        #pragma unroll
        for (int fb = 0; fb < 4; ++fb)
            #pragma unroll
            for (int r = 0; r < 4; ++r)
                mbuf[mb + fb * 4 + r] = acc[fb][r];
        #pragma unroll
        for (int r = 0; r < 4; ++r)
            mbuf[mb + 16 + r] = accd[r];
    }
    __syncthreads();
    if (grp == 0) {
        #pragma unroll
        for (int fb = 0; fb < 4; ++fb)
            #pragma unroll
            for (int r = 0; r < 4; ++r)
                acc[fb][r] += mbuf[mb + fb * 4 + r];
        #pragma unroll
        for (int r = 0; r < 4; ++r)
            accd[r] += mbuf[mb + 16 + r];
        #pragma unroll
        for (int r = 0; r < 4; ++r) {
            float inv = 1.0f / accd[r];
            int orow = i0 + wrow * 16 + g * 4 + r;
            float* op = out + (size_t)orow * OUT_F + head * HF + ar;
            #pragma unroll
            for (int fb = 0; fb < 4; ++fb)
                op[fb * 16] += acc[fb][r] * inv;
        }
    }
}

extern "C" void kernel_launch(void* const* d_in, const int* in_sizes, int n_in,
                              void* d_out, int out_size, void* d_ws, size_t ws_size,
                              hipStream_t stream) {
    const float* x     = (const float*)d_in[0];
    const int*   graph = (const int*)d_in[1];
    const float* w     = (const float*)d_in[2];
    const float* wi    = (const float*)d_in[3];
    const float* wj    = (const float*)d_in[4];
    const float* wr    = (const float*)d_in[5];
    const float* bias  = (const float*)d_in[6];
    float* out = (float*)d_out;

    char* ws = (char*)d_ws;
    unsigned short* h   = (unsigned short*)(ws);
    unsigned short* hT  = (unsigned short*)(ws + (4u << 20));
    float* coe_i = (float*)(ws + (8u << 20));
    float* coe_j = (float*)(ws + (8u << 20) + 131072);
    float* maxB  = (float*)(ws + (8u << 20) + 2 * 131072);
    float* F     = (float*)(ws + (8u << 20) + 2 * 131072 + 1024);
    float* H     = (float*)(ws + (8u << 20) + 3 * 131072 + 1024);
    unsigned short* BbT = (unsigned short*)(ws + (8u << 20) + 4 * 131072 + 1024);
    unsigned int* bits  = (unsigned int*)(ws + (8u << 20) + 4 * 131072 + 1024 + 262144);

    k_wcvt<<<dim3(512), 256, 0, stream>>>(w, wr, BbT);
    k_gemm<<<dim3(128, 4), 256, 0, stream>>>(x, BbT, bias, h, out);
    k_tr<<<dim3(128, 4), 256, 0, stream>>>(h, wi, wj, hT, coe_i, coe_j);
    k_cols<<<dim3(4), 256, 0, stream>>>(coe_j, maxB, F, H);
    k_pack<<<dim3(256, 32), 256, 0, stream>>>(graph, bits);
    k_att<<<dim3(HEADS, N / 64), 512, 0, stream>>>(hT, coe_i, maxB, F, H, bits, out);
}